// Round 10
// baseline (80.019 us; speedup 1.0000x reference)
//
#include <hip/hip_runtime.h>

// out[1024][1024] = relu(a @ feats^T) @ relu(b @ feats^T)^T
//   a,b: [1024][2048] fp32, feats: [128][2048] fp32, out fp32.
// Pipeline (3 dispatches — proven best shape; R10 change: gemm1 TLP x2):
//   gemm1_part8: grid (128,8) = 16-row M-stripes x 8 K-splits (K=256, 4 iters
//                of 64) -> fp32 partials part[8][2048][128] (8 MB).
//                1024 blocks (~4/CU) so latency is hidden by co-resident
//                blocks (R4/R9's 512 blocks = 2/CU was latency-idle bound:
//                Occ 17%, VALUBusy 1%).
//   reduce_relu: sum 8 partials, relu, cvt -> bf16 fk[2048][128] (512 KB)
//   gemm2      : 64x64 out tiles via MFMA on relu'd bf16 fk
// Measured lessons: grid.sync (R1), per-elem atomics (R2), consumer-fused
// reduce (R5/R5-analysis: partials are cross-XCD -> L3-speed reads, 8-16x
// amp), producer fence+ctr (R6: per-block L2 writeback), full-K-per-block
// (R3/R7/R8) all lose to split-K + plain dispatches. Staging fully
// coalesced (R8/R9). ~42 us ws poison-fill is a fixed term.

typedef __attribute__((ext_vector_type(8))) __bf16 bf16x8;
typedef __attribute__((ext_vector_type(4))) __bf16 bf16x4;
typedef __attribute__((ext_vector_type(4))) float floatx4;

#define KD     2048   // inner K of gemm1
#define NF     128    // feature count = K of gemm2
#define NA     1024   // rows of a (= rows of b = out dim)
#define NPART  8      // K-splits (K=256 each)
#define KSL    256    // K per split
#define FKN    (2048 * 128)

static __device__ inline bf16x4 cvt4(float4 u) {
    bf16x4 s;
    s[0] = (__bf16)u.x; s[1] = (__bf16)u.y; s[2] = (__bf16)u.z; s[3] = (__bf16)u.w;
    return s;
}

// ---- gemm1_part8: part[s][m0:m0+16][0:128] = X[m0:m0+16, s*256:(s+1)*256] . feats^T
// block = 4 waves; wave w covers feat-cols [w*32, w*32+32). 4 K-iters of 64.
// Staging fully coalesced: each wave-instr reads 4 consecutive rows x 256
// contiguous bytes (16 float4 lanes per row).
__global__ __launch_bounds__(256) void gemm1_part8(const float* __restrict__ A,
                                                   const float* __restrict__ B,
                                                   const float* __restrict__ F,
                                                   float* __restrict__ part) {
    __shared__ __bf16 Xs[16 * 72];    // 16 rows x 64 K-cols, stride 72
    __shared__ __bf16 Fs[128 * 72];   // 128 feat-rows x 64 K-cols

    const int t    = threadIdx.x;
    const int m0   = blockIdx.x * 16;
    const int s    = blockIdx.y;
    const int k0   = s * KSL;
    const float* src = (m0 < NA) ? (A + (size_t)m0 * KD)
                                 : (B + (size_t)(m0 - NA) * KD);

    const int lane = t & 63;
    const int w    = t >> 6;
    const int ln   = lane & 15;
    const int quad = lane >> 4;
    const int q8   = quad * 8;

    floatx4 acc[2];
    acc[0] = (floatx4){0.f, 0.f, 0.f, 0.f};
    acc[1] = (floatx4){0.f, 0.f, 0.f, 0.f};

    // coalesced staging coordinates (shared by X and F)
    const int srow = t >> 4;          // 0..15
    const int scol = (t & 15) * 4;    // float col 0..60 within the 64-col chunk
    const float* xp = src + (size_t)srow * KD + (k0 + scol);  // X: 1 float4/thr
    const float* fp = F   + (size_t)srow * KD + (k0 + scol);  // F rows srow + 16*i

    // register prefetch of kk=0
    float4 x0 = *(const float4*)(xp);
    float4 fa[8];
#pragma unroll
    for (int i = 0; i < 8; i++)
        fa[i] = *(const float4*)(fp + (size_t)i * 16 * KD);

#pragma unroll
    for (int kk = 0; kk < KSL; kk += 64) {
        *(bf16x4*)&Xs[srow * 72 + scol] = cvt4(x0);
#pragma unroll
        for (int i = 0; i < 8; i++)
            *(bf16x4*)&Fs[(i * 16 + srow) * 72 + scol] = cvt4(fa[i]);
        __syncthreads();

        if (kk + 64 < KSL) {   // prefetch next K-chunk while MFMAs run
            x0 = *(const float4*)(xp + kk + 64);
#pragma unroll
            for (int i = 0; i < 8; i++)
                fa[i] = *(const float4*)(fp + (size_t)i * 16 * KD + kk + 64);
        }

#pragma unroll
        for (int sub = 0; sub < 64; sub += 32) {
            bf16x8 af = *(const bf16x8*)&Xs[ln * 72 + sub + q8];
#pragma unroll
            for (int nt = 0; nt < 2; nt++) {
                bf16x8 bfrag = *(const bf16x8*)&Fs[(w * 32 + nt * 16 + ln) * 72 + sub + q8];
                acc[nt] = __builtin_amdgcn_mfma_f32_16x16x32_bf16(
                    af, bfrag, acc[nt], 0, 0, 0);
            }
        }
        __syncthreads();
    }

    float* pdst = part + (size_t)s * FKN;
#pragma unroll
    for (int nt = 0; nt < 2; nt++)
#pragma unroll
        for (int r = 0; r < 4; r++) {
            int row = m0 + quad * 4 + r;
            int col = w * 32 + nt * 16 + ln;
            pdst[(size_t)row * NF + col] = acc[nt][r];
        }
}

// ---- reduce_relu: fkb[i] = bf16(relu(sum_s part[s][i])), vectorized x4 ----
__global__ __launch_bounds__(256) void reduce_relu(const float* __restrict__ part,
                                                   __bf16* __restrict__ fkb) {
    int idx = blockIdx.x * 256 + threadIdx.x;   // 65536 threads, 4 floats each
    size_t base = (size_t)idx * 4;
    float4 sum = make_float4(0.f, 0.f, 0.f, 0.f);
#pragma unroll
    for (int s = 0; s < NPART; s++) {
        float4 u = *(const float4*)(part + (size_t)s * FKN + base);
        sum.x += u.x; sum.y += u.y; sum.z += u.z; sum.w += u.w;
    }
    bf16x4 o;
    o[0] = (__bf16)fmaxf(sum.x, 0.f);
    o[1] = (__bf16)fmaxf(sum.y, 0.f);
    o[2] = (__bf16)fmaxf(sum.z, 0.f);
    o[3] = (__bf16)fmaxf(sum.w, 0.f);
    *(bf16x4*)(fkb + base) = o;
}

// ---- gemm2: out[i][j] = sum_f fkb[i][f] * fkb[1024+j][f] (already relu'd) ----
// grid (16,16): 64x64 out tiles; block = 4 waves in 2x2. (R4-verbatim)
__global__ __launch_bounds__(256) void gemm2(const __bf16* __restrict__ fkb,
                                             float* __restrict__ out) {
    __shared__ __bf16 Ps[64 * 136];
    __shared__ __bf16 Qs[64 * 136];

    const int t    = threadIdx.x;
    const int i0   = blockIdx.y * 64;
    const int j0   = blockIdx.x * 64;
    const int lane = t & 63;
    const int w    = t >> 6;
    const int wm   = w & 1;
    const int wn   = w >> 1;
    const int ln   = lane & 15;
    const int quad = lane >> 4;
    const int q8   = quad * 8;

    const int prow = t >> 2, pcol = (t & 3) * 32;
    {
        const __bf16* p = fkb + (size_t)(i0 + prow) * NF + pcol;
        const __bf16* q = fkb + (size_t)(NA + j0 + prow) * NF + pcol;
#pragma unroll
        for (int c = 0; c < 32; c += 8) {
            *(bf16x8*)&Ps[prow * 136 + pcol + c] = *(const bf16x8*)(p + c);
            *(bf16x8*)&Qs[prow * 136 + pcol + c] = *(const bf16x8*)(q + c);
        }
    }
    __syncthreads();

    floatx4 acc[2][2];
#pragma unroll
    for (int mt = 0; mt < 2; mt++)
#pragma unroll
        for (int nt = 0; nt < 2; nt++)
            acc[mt][nt] = (floatx4){0.f, 0.f, 0.f, 0.f};

#pragma unroll
    for (int k0 = 0; k0 < 128; k0 += 32) {
        bf16x8 af[2], bf[2];
#pragma unroll
        for (int mt = 0; mt < 2; mt++)
            af[mt] = *(const bf16x8*)&Ps[(wm * 32 + mt * 16 + ln) * 136 + k0 + q8];
#pragma unroll
        for (int nt = 0; nt < 2; nt++)
            bf[nt] = *(const bf16x8*)&Qs[(wn * 32 + nt * 16 + ln) * 136 + k0 + q8];
#pragma unroll
        for (int mt = 0; mt < 2; mt++)
#pragma unroll
            for (int nt = 0; nt < 2; nt++)
                acc[mt][nt] = __builtin_amdgcn_mfma_f32_16x16x32_bf16(
                    af[mt], bf[nt], acc[mt][nt], 0, 0, 0);
    }

#pragma unroll
    for (int mt = 0; mt < 2; mt++)
#pragma unroll
        for (int nt = 0; nt < 2; nt++)
#pragma unroll
            for (int r = 0; r < 4; r++) {
                int row = i0 + wm * 32 + mt * 16 + quad * 4 + r;
                int col = j0 + wn * 32 + nt * 16 + ln;
                out[(size_t)row * 1024 + col] = acc[mt][nt][r];
            }
}

extern "C" void kernel_launch(void* const* d_in, const int* in_sizes, int n_in,
                              void* d_out, int out_size, void* d_ws, size_t ws_size,
                              hipStream_t stream) {
    const float* a     = (const float*)d_in[0];
    const float* b     = (const float*)d_in[1];
    const float* feats = (const float*)d_in[2];
    float* out = (float*)d_out;

    float*   part = (float*)d_ws;                                      // 8 MB fp32 partials
    __bf16*  fkb  = (__bf16*)((char*)d_ws + (size_t)NPART * FKN * 4);  // 512 KB bf16

    gemm1_part8<<<dim3(128, NPART), 256, 0, stream>>>(a, b, feats, part);
    reduce_relu<<<256, 256, 0, stream>>>(part, fkb);
    gemm2<<<dim3(16, 16), 256, 0, stream>>>(fkb, out);
}

// Round 11
// 77.912 us; speedup vs baseline: 1.0270x; 1.0270x over previous
//
#include <hip/hip_runtime.h>

// out[1024][1024] = relu(a @ feats^T) @ relu(b @ feats^T)^T
//   a,b: [1024][2048] fp32, feats: [128][2048] fp32, out fp32.
// Pipeline (3 dispatches — proven shape; R11 change: gemm1 single-barrier):
//   gemm1_onebar: grid (32,8) = 64-row M-stripes x 8 K-splits. 256 blocks =
//                 1/CU, 108 KB LDS holds the block's ENTIRE K=256 slice; all
//                 staging loads issued in a 2-deep reg ping-pong (no barriers
//                 between chunks), ONE __syncthreads, then 64 uninterrupted
//                 MFMAs. Kills the per-iteration latency exposure that made
//                 gemm1 ~13 us (R4/R9: 8 barriers, 4 exposed round-trips).
//   reduce_relu : sum 8 partials, relu, cvt -> bf16 fk[2048][128] (512 KB)
//   gemm2       : 64x64 out tiles via MFMA on relu'd bf16 fk (R4-verbatim)
// Measured lessons: grid.sync (R1), per-elem atomics (R2), consumer-fused
// reduce (R5: 16x amp), producer fence+ctr (R6: L2 writeback), full-K-per-
// block (R3/R7/R8), TLP-x2 16-row stripes (R10) all lose. Staging fully
// coalesced (R8/R9). ~42 us ws poison-fill is a fixed term.

typedef __attribute__((ext_vector_type(8))) __bf16 bf16x8;
typedef __attribute__((ext_vector_type(4))) __bf16 bf16x4;
typedef __attribute__((ext_vector_type(4))) float floatx4;

#define KD     2048   // inner K of gemm1
#define NF     128    // feature count = K of gemm2
#define NA     1024   // rows of a (= rows of b = out dim)
#define NPART  8      // K-splits (K=256 each)
#define KSL    256    // K per split
#define FKN    (2048 * 128)

#define XSZ    (64 * 72)    // bf16 elems per X chunk buffer
#define FSZ    (128 * 72)   // bf16 elems per F chunk buffer

static __device__ inline bf16x4 cvt4(float4 u) {
    bf16x4 s;
    s[0] = (__bf16)u.x; s[1] = (__bf16)u.y; s[2] = (__bf16)u.z; s[3] = (__bf16)u.w;
    return s;
}

struct Chunk {
    float4 x[4];   // X rows srow+16j, j=0..3
    float4 f[8];   // F rows srow+16i, i=0..7
};

static __device__ inline void load_chunk(Chunk& ch, const float* xp,
                                         const float* fp, int koff) {
#pragma unroll
    for (int j = 0; j < 4; j++)
        ch.x[j] = *(const float4*)(xp + (size_t)j * 16 * KD + koff);
#pragma unroll
    for (int i = 0; i < 8; i++)
        ch.f[i] = *(const float4*)(fp + (size_t)i * 16 * KD + koff);
}

static __device__ inline void write_chunk(const Chunk& ch, __bf16* Xc, __bf16* Fc,
                                          int srow, int scol) {
#pragma unroll
    for (int j = 0; j < 4; j++)
        *(bf16x4*)&Xc[(srow + 16 * j) * 72 + scol] = cvt4(ch.x[j]);
#pragma unroll
    for (int i = 0; i < 8; i++)
        *(bf16x4*)&Fc[(srow + 16 * i) * 72 + scol] = cvt4(ch.f[i]);
}

// ---- gemm1_onebar: part[s][m0:m0+64][0:128] = X[m0:m0+64, s*256:+256] . feats^T
// block = 4 waves; wave w covers feat-cols [w*32, w*32+32). acc[4][2].
__global__ __launch_bounds__(256) void gemm1_onebar(const float* __restrict__ A,
                                                    const float* __restrict__ B,
                                                    const float* __restrict__ F,
                                                    float* __restrict__ part) {
    __shared__ __attribute__((aligned(16))) __bf16 smem[4 * XSZ + 4 * FSZ]; // 108 KB
    __bf16* Xs = smem;              // 4 chunks of [64][72]
    __bf16* Fs = smem + 4 * XSZ;    // 4 chunks of [128][72]

    const int t    = threadIdx.x;
    const int m0   = blockIdx.x * 64;
    const int s    = blockIdx.y;
    const int k0   = s * KSL;
    const float* src = (m0 < NA) ? (A + (size_t)m0 * KD)
                                 : (B + (size_t)(m0 - NA) * KD);

    const int lane = t & 63;
    const int w    = t >> 6;
    const int ln   = lane & 15;
    const int quad = lane >> 4;
    const int q8   = quad * 8;

    // coalesced staging coordinates (shared by X and F)
    const int srow = t >> 4;          // 0..15
    const int scol = (t & 15) * 4;    // float col 0..60 within a 64-col chunk
    const float* xp = src + (size_t)srow * KD + (k0 + scol);  // X rows srow+16j
    const float* fp = F   + (size_t)srow * KD + (k0 + scol);  // F rows srow+16i

    // 2-deep ping-pong: chunk c+1's loads are in flight while c writes to LDS
    Chunk ca, cb;
    load_chunk(ca, xp, fp, 0);
    load_chunk(cb, xp, fp, 64);
    write_chunk(ca, Xs + 0 * XSZ, Fs + 0 * FSZ, srow, scol);
    load_chunk(ca, xp, fp, 128);
    write_chunk(cb, Xs + 1 * XSZ, Fs + 1 * FSZ, srow, scol);
    load_chunk(cb, xp, fp, 192);
    write_chunk(ca, Xs + 2 * XSZ, Fs + 2 * FSZ, srow, scol);
    write_chunk(cb, Xs + 3 * XSZ, Fs + 3 * FSZ, srow, scol);
    __syncthreads();   // the ONLY barrier

    floatx4 acc[4][2];
#pragma unroll
    for (int mt = 0; mt < 4; mt++)
#pragma unroll
        for (int nt = 0; nt < 2; nt++)
            acc[mt][nt] = (floatx4){0.f, 0.f, 0.f, 0.f};

#pragma unroll
    for (int c = 0; c < 4; c++) {
        const __bf16* Xc = Xs + c * XSZ;
        const __bf16* Fc = Fs + c * FSZ;
#pragma unroll
        for (int sub = 0; sub < 64; sub += 32) {
            bf16x8 bfrag[2];
#pragma unroll
            for (int nt = 0; nt < 2; nt++)
                bfrag[nt] = *(const bf16x8*)&Fc[(w * 32 + nt * 16 + ln) * 72 + sub + q8];
#pragma unroll
            for (int mt = 0; mt < 4; mt++) {
                bf16x8 af = *(const bf16x8*)&Xc[(mt * 16 + ln) * 72 + sub + q8];
#pragma unroll
                for (int nt = 0; nt < 2; nt++)
                    acc[mt][nt] = __builtin_amdgcn_mfma_f32_16x16x32_bf16(
                        af, bfrag[nt], acc[mt][nt], 0, 0, 0);
            }
        }
    }

    float* pdst = part + (size_t)s * FKN;
#pragma unroll
    for (int mt = 0; mt < 4; mt++)
#pragma unroll
        for (int nt = 0; nt < 2; nt++)
#pragma unroll
            for (int r = 0; r < 4; r++) {
                int row = m0 + mt * 16 + quad * 4 + r;
                int col = w * 32 + nt * 16 + ln;
                pdst[(size_t)row * NF + col] = acc[mt][nt][r];
            }
}

// ---- reduce_relu: fkb[i] = bf16(relu(sum_s part[s][i])), vectorized x4 ----
__global__ __launch_bounds__(256) void reduce_relu(const float* __restrict__ part,
                                                   __bf16* __restrict__ fkb) {
    int idx = blockIdx.x * 256 + threadIdx.x;   // 65536 threads, 4 floats each
    size_t base = (size_t)idx * 4;
    float4 sum = make_float4(0.f, 0.f, 0.f, 0.f);
#pragma unroll
    for (int s = 0; s < NPART; s++) {
        float4 u = *(const float4*)(part + (size_t)s * FKN + base);
        sum.x += u.x; sum.y += u.y; sum.z += u.z; sum.w += u.w;
    }
    bf16x4 o;
    o[0] = (__bf16)fmaxf(sum.x, 0.f);
    o[1] = (__bf16)fmaxf(sum.y, 0.f);
    o[2] = (__bf16)fmaxf(sum.z, 0.f);
    o[3] = (__bf16)fmaxf(sum.w, 0.f);
    *(bf16x4*)(fkb + base) = o;
}

// ---- gemm2: out[i][j] = sum_f fkb[i][f] * fkb[1024+j][f] (already relu'd) ----
// grid (16,16): 64x64 out tiles; block = 4 waves in 2x2. (R4-verbatim)
__global__ __launch_bounds__(256) void gemm2(const __bf16* __restrict__ fkb,
                                             float* __restrict__ out) {
    __shared__ __bf16 Ps[64 * 136];
    __shared__ __bf16 Qs[64 * 136];

    const int t    = threadIdx.x;
    const int i0   = blockIdx.y * 64;
    const int j0   = blockIdx.x * 64;
    const int lane = t & 63;
    const int w    = t >> 6;
    const int wm   = w & 1;
    const int wn   = w >> 1;
    const int ln   = lane & 15;
    const int quad = lane >> 4;
    const int q8   = quad * 8;

    const int prow = t >> 2, pcol = (t & 3) * 32;
    {
        const __bf16* p = fkb + (size_t)(i0 + prow) * NF + pcol;
        const __bf16* q = fkb + (size_t)(NA + j0 + prow) * NF + pcol;
#pragma unroll
        for (int c = 0; c < 32; c += 8) {
            *(bf16x8*)&Ps[prow * 136 + pcol + c] = *(const bf16x8*)(p + c);
            *(bf16x8*)&Qs[prow * 136 + pcol + c] = *(const bf16x8*)(q + c);
        }
    }
    __syncthreads();

    floatx4 acc[2][2];
#pragma unroll
    for (int mt = 0; mt < 2; mt++)
#pragma unroll
        for (int nt = 0; nt < 2; nt++)
            acc[mt][nt] = (floatx4){0.f, 0.f, 0.f, 0.f};

#pragma unroll
    for (int k0 = 0; k0 < 128; k0 += 32) {
        bf16x8 af[2], bf[2];
#pragma unroll
        for (int mt = 0; mt < 2; mt++)
            af[mt] = *(const bf16x8*)&Ps[(wm * 32 + mt * 16 + ln) * 136 + k0 + q8];
#pragma unroll
        for (int nt = 0; nt < 2; nt++)
            bf[nt] = *(const bf16x8*)&Qs[(wn * 32 + nt * 16 + ln) * 136 + k0 + q8];
#pragma unroll
        for (int mt = 0; mt < 2; mt++)
#pragma unroll
            for (int nt = 0; nt < 2; nt++)
                acc[mt][nt] = __builtin_amdgcn_mfma_f32_16x16x32_bf16(
                    af[mt], bf[nt], acc[mt][nt], 0, 0, 0);
    }

#pragma unroll
    for (int mt = 0; mt < 2; mt++)
#pragma unroll
        for (int nt = 0; nt < 2; nt++)
#pragma unroll
            for (int r = 0; r < 4; r++) {
                int row = i0 + wm * 32 + mt * 16 + quad * 4 + r;
                int col = j0 + wn * 32 + nt * 16 + ln;
                out[(size_t)row * 1024 + col] = acc[mt][nt][r];
            }
}

extern "C" void kernel_launch(void* const* d_in, const int* in_sizes, int n_in,
                              void* d_out, int out_size, void* d_ws, size_t ws_size,
                              hipStream_t stream) {
    const float* a     = (const float*)d_in[0];
    const float* b     = (const float*)d_in[1];
    const float* feats = (const float*)d_in[2];
    float* out = (float*)d_out;

    float*   part = (float*)d_ws;                                      // 8 MB fp32 partials
    __bf16*  fkb  = (__bf16*)((char*)d_ws + (size_t)NPART * FKN * 4);  // 512 KB bf16

    gemm1_onebar<<<dim3(32, NPART), 256, 0, stream>>>(a, b, feats, part);
    reduce_relu<<<256, 256, 0, stream>>>(part, fkb);
    gemm2<<<dim3(16, 16), 256, 0, stream>>>(fkb, out);
}